// Round 24
// baseline (112.571 us; speedup 1.0000x reference)
//
#include <hip/hip_runtime.h>
#include <hip/hip_bf16.h>

#define NJ 24
#define NV 6890
#define NVP 6912
#define NR (NV*3)        // 20670 output rows per batch
#define NPF 207
#define KB 217           // 207 pf + 10 beta
#define KP 256           // padded K (8 x 32)
#define NT 162           // 128-col tiles (fallback path)
#define NT2 108          // 192-col tiles (64 whole verts each)
#define NSPLIT 256       // jdirs v-splits
#define VPB 27           // ceil(6890/256)
#define FTILE 32768      // A-tile shorts: 8 ks * 8 frag * 64 lane * 8
#define FT2   49152      // B-tile shorts (192-col)
#define ELDW 264         // elds row stride in shorts (64 verts*4 + 8 pad)

typedef short s16x8 __attribute__((ext_vector_type(8)));
typedef short s16x4 __attribute__((ext_vector_type(4)));
typedef float f32x4 __attribute__((ext_vector_type(4)));
typedef float f4u   __attribute__((ext_vector_type(4), aligned(4)));

__device__ constexpr int PAR[24] = {-1,0,0,0,1,2,3,4,5,6,7,8,9,9,9,12,13,14,16,17,18,19,20,21};

__device__ __forceinline__ short f2bf(float f) {
    __hip_bfloat16 h = __float2bfloat16(f);
    return *reinterpret_cast<short*>(&h);
}
__device__ __forceinline__ float bf2fs(unsigned short u) {
    unsigned int x = ((unsigned int)u) << 16;
    return __uint_as_float(x);
}

// A-fragment address for (row_in_tile, k)
__device__ __forceinline__ size_t frag_addr(int row128, int k) {
    int ks = k >> 5, q = (k >> 3) & 3, e = k & 7;
    int mf = row128 >> 4, r16 = row128 & 15;
    return ((size_t)(ks*8 + mf) * 64 + q*16 + r16) * 8 + e;
}

// -------- device bodies shared by fat kernel and fallbacks --------
__device__ __forceinline__ void rodrigues_body(int idx, const float* __restrict__ theta,
        const float* __restrict__ beta, float* __restrict__ Rws,
        float* __restrict__ pfA, short* __restrict__ Afrag, int B) {
    if (idx >= B * NJ) return;
    int b = idx / NJ, j = idx % NJ;
    float x = theta[b*72 + j*3 + 0];
    float y = theta[b*72 + j*3 + 1];
    float z = theta[b*72 + j*3 + 2];
    float n = sqrtf(x*x + y*y + z*z);
    float a = fmaxf(n, 1e-8f);
    float inv = 1.0f / a;
    float ix = x*inv, iy = y*inv, iz = z*inv;
    float c = cosf(a), s = sinf(a), t = 1.0f - c;
    float r[9];
    r[0] = t*ix*ix + c;     r[1] = t*ix*iy - s*iz;  r[2] = t*ix*iz + s*iy;
    r[3] = t*ix*iy + s*iz;  r[4] = t*iy*iy + c;     r[5] = t*iy*iz - s*ix;
    r[6] = t*ix*iz - s*iy;  r[7] = t*iy*iz + s*ix;  r[8] = t*iz*iz + c;
    float* Rp = Rws + (size_t)idx * 9;
    #pragma unroll
    for (int k = 0; k < 9; ++k) Rp[k] = r[k];

    int rb = b & 127;
    short* At = Afrag + (size_t)(b >> 7) * FTILE;
    float* pa = pfA + (size_t)b * 224;
    if (j >= 1) {
        #pragma unroll
        for (int kk = 0; kk < 9; ++kk) {
            int k = (j-1)*9 + kk;
            float f = r[kk] - ((kk == 0 || kk == 4 || kk == 8) ? 1.0f : 0.0f);
            At[frag_addr(rb, k)] = f2bf(f);
            pa[k] = f;
        }
    } else {
        #pragma unroll
        for (int kk = 0; kk < 10; ++kk) {
            int k = NPF + kk;
            float f = beta[b*10 + kk];
            At[frag_addr(rb, k)] = f2bf(f);
            pa[k] = f;
        }
        for (int k = KB; k < KP; ++k)
            At[frag_addr(rb, k)] = 0;
    }
}

__device__ __forceinline__ void convB192_body(int nt, int id,
        const float* __restrict__ pd, const float* __restrict__ sd,
        short* __restrict__ Bf) {
    int lane_ = id & 63;
    int fi = id >> 6;
    int nf = fi % 12, ks = fi / 12;
    int q = lane_ >> 4, r16 = lane_ & 15;
    int rg = nt*192 + nf*16 + r16;
    int k0 = ks*32 + q*8;
    s16x8 v;
    if (rg < NR) {
        if (k0 + 7 < NPF) {
            const float* p = pd + (size_t)rg * NPF + k0;
            #pragma unroll
            for (int k = 0; k < 8; ++k) v[k] = f2bf(p[k]);
        } else {
            #pragma unroll
            for (int k = 0; k < 8; ++k) {
                int col = k0 + k;
                float f = 0.0f;
                if (col < NPF)     f = pd[(size_t)rg * NPF + col];
                else if (col < KB) f = sd[(size_t)rg * 10 + (col - NPF)];
                v[k] = f2bf(f);
            }
        }
    } else {
        #pragma unroll
        for (int k = 0; k < 8; ++k) v[k] = 0;
    }
    *(s16x8*)&Bf[((size_t)nt * FT2) + (size_t)id * 8] = v;
}

// ============ K0: fat prep kernel — jdirs | convB192 | rodrigues ============
__global__ __launch_bounds__(256) void k_prep(const float* __restrict__ theta,
        const float* __restrict__ beta, const float* __restrict__ pd,
        const float* __restrict__ sd, const float* __restrict__ vt,
        const float* __restrict__ Jreg,
        float* __restrict__ Rws, float* __restrict__ pfA, short* __restrict__ Afrag,
        short* __restrict__ Bf, float* __restrict__ part, int B) {
    __shared__ float wjs[24][VPB];
    const int bid = blockIdx.x;
    const int t = threadIdx.x;
    if (bid < NSPLIT) {
        // ---- jdirs ----
        int bi = bid;
        int v0 = bi * VPB;
        int nv = NV - v0; if (nv > VPB) nv = VPB; if (nv < 0) nv = 0;
        for (int i = t; i < 24*VPB; i += 256) {
            int j = i / VPB, vv = i - j*VPB;
            wjs[j][vv] = (vv < nv) ? Jreg[(size_t)j * NV + v0 + vv] : 0.0f;
        }
        __syncthreads();
        int k = t;
        float acc[72];
        #pragma unroll
        for (int i = 0; i < 72; ++i) acc[i] = 0.0f;
        for (int vv = 0; vv < VPB; ++vv) {
            int v = v0 + vv;
            if (v >= NV) break;
            #pragma unroll
            for (int c = 0; c < 3; ++c) {
                int row = v*3 + c;
                float val = 0.0f;
                if (k < NPF)      val = pd[(size_t)row * NPF + k];
                else if (k < KB)  val = sd[(size_t)row * 10 + (k - NPF)];
                else if (k == KB) val = vt[row];
                #pragma unroll
                for (int j = 0; j < 24; ++j) acc[j*3 + c] += wjs[j][vv] * val;
            }
        }
        if (k < 224) {
            float* p = part + (size_t)bi * (72*224);
            #pragma unroll
            for (int i = 0; i < 72; ++i) p[i*224 + k] = acc[i];
        }
    } else if (bid < NSPLIT + 24*NT2) {
        // ---- convB192 ----
        int cb = bid - NSPLIT;
        int nt = cb / 24;
        int id = (cb % 24) * 256 + t;
        convB192_body(nt, id, pd, sd, Bf);
    } else {
        // ---- rodrigues ----
        int idx = (bid - NSPLIT - 24*NT2) * 256 + t;
        rodrigues_body(idx, theta, beta, Rws, pfA, Afrag, B);
    }
}

// ============ standalone kernels for fallback path ============
__global__ __launch_bounds__(256) void k_rodrigues(const float* __restrict__ theta,
        const float* __restrict__ beta, float* __restrict__ Rws,
        float* __restrict__ pfA, short* __restrict__ Afrag, int B) {
    rodrigues_body(blockIdx.x * blockDim.x + threadIdx.x, theta, beta, Rws, pfA, Afrag, B);
}

__global__ __launch_bounds__(256) void k_convB128(const float* __restrict__ pd,
        const float* __restrict__ sd, short* __restrict__ Bf) {
    int cid = blockIdx.x * 256 + threadIdx.x;
    int lane_ = cid & 63;
    int nf = (cid >> 6) & 7;
    int ks = (cid >> 9) & 7;
    int nt = cid >> 12;
    int q = lane_ >> 4, r16 = lane_ & 15;
    int rg = nt*128 + nf*16 + r16;
    int k0 = ks*32 + q*8;
    s16x8 v;
    if (rg < NR) {
        if (k0 + 7 < NPF) {
            const float* p = pd + (size_t)rg * NPF + k0;
            #pragma unroll
            for (int k = 0; k < 8; ++k) v[k] = f2bf(p[k]);
        } else {
            #pragma unroll
            for (int k = 0; k < 8; ++k) {
                int col = k0 + k;
                float f = 0.0f;
                if (col < NPF)     f = pd[(size_t)rg * NPF + col];
                else if (col < KB) f = sd[(size_t)rg * 10 + (col - NPF)];
                v[k] = f2bf(f);
            }
        }
    } else {
        #pragma unroll
        for (int k = 0; k < 8; ++k) v[k] = 0;
    }
    *(s16x8*)&Bf[(size_t)cid * 8] = v;
}

__global__ __launch_bounds__(256) void k_jdirs(const float* __restrict__ pd,
        const float* __restrict__ sd, const float* __restrict__ vt,
        const float* __restrict__ Jreg, float* __restrict__ part) {
    __shared__ float wjs[24][VPB];
    int bi = blockIdx.x;
    int v0 = bi * VPB;
    int nv = NV - v0; if (nv > VPB) nv = VPB; if (nv < 0) nv = 0;
    for (int i = threadIdx.x; i < 24*VPB; i += 256) {
        int j = i / VPB, vv = i - j*VPB;
        wjs[j][vv] = (vv < nv) ? Jreg[(size_t)j * NV + v0 + vv] : 0.0f;
    }
    __syncthreads();
    int k = threadIdx.x;
    float acc[72];
    #pragma unroll
    for (int i = 0; i < 72; ++i) acc[i] = 0.0f;
    for (int vv = 0; vv < VPB; ++vv) {
        int v = v0 + vv;
        if (v >= NV) break;
        #pragma unroll
        for (int c = 0; c < 3; ++c) {
            int row = v*3 + c;
            float val = 0.0f;
            if (k < NPF)      val = pd[(size_t)row * NPF + k];
            else if (k < KB)  val = sd[(size_t)row * 10 + (k - NPF)];
            else if (k == KB) val = vt[row];
            #pragma unroll
            for (int j = 0; j < 24; ++j) acc[j*3 + c] += wjs[j][vv] * val;
        }
    }
    if (k < 224) {
        float* p = part + (size_t)bi * (72*224);
        #pragma unroll
        for (int i = 0; i < 72; ++i) p[i*224 + k] = acc[i];
    }
}

// ============ K4a: reduce 256 -> 8 partials ============
__global__ __launch_bounds__(256) void k_jreduce1(const float* __restrict__ part,
        float* __restrict__ part2) {
    int i = blockIdx.x;            // 0..71
    int s = blockIdx.y;            // 0..7
    int k = threadIdx.x;
    if (k >= 224) return;
    float acc = 0.0f;
    #pragma unroll 4
    for (int bi = s*32; bi < s*32 + 32; ++bi)
        acc += part[(size_t)bi * (72*224) + i*224 + k];
    part2[((size_t)s * 72 + i) * 224 + k] = acc;
}

// ============ K4b: reduce 8 -> JDt[k][72] ============
__global__ __launch_bounds__(256) void k_jreduce2(const float* __restrict__ part2,
        float* __restrict__ JDt) {
    int e = blockIdx.x * 256 + threadIdx.x;
    if (e >= 72*224) return;
    int i = e / 224, k = e - i*224;
    float s = 0.0f;
    #pragma unroll
    for (int ss = 0; ss < 8; ++ss)
        s += part2[((size_t)ss * 72 + i) * 224 + k];
    if (k < 218) JDt[k*72 + i] = s;
}

// ============ K5: J ============
__global__ __launch_bounds__(128) void k_J(const float* __restrict__ pfA,
        const float* __restrict__ JDt, float* __restrict__ Jout, int B) {
    int b = blockIdx.x, t = threadIdx.x;
    if (t >= 72) return;
    const float* pa = pfA + (size_t)b * 224;
    float acc = JDt[217*72 + t];
    #pragma unroll 7
    for (int k = 0; k < KB; ++k) acc += pa[k] * JDt[k*72 + t];
    Jout[(size_t)b * 72 + t] = acc;
}

// ============ K6: kinematic chain -> G_corr (+ optional Gmf fragments) ============
__global__ __launch_bounds__(32) void k_chain(const float* __restrict__ Rg,
        const float* __restrict__ Jg, float* __restrict__ Gc,
        short* __restrict__ Gmf, int doGmf, int B) {
    __shared__ float Gs[32 * 289];
    int b = blockIdx.x * 32 + threadIdx.x;
    if (b >= B) return;
    float* G = &Gs[threadIdx.x * 289];
    float Jl[72];
    const float* Jb = Jg + (size_t)b * 72;
    #pragma unroll
    for (int i = 0; i < 72; ++i) Jl[i] = Jb[i];
    const float* Rb = Rg + (size_t)b * 216;
    G[0]=Rb[0]; G[1]=Rb[1]; G[2]=Rb[2];  G[3]=Jl[0];
    G[4]=Rb[3]; G[5]=Rb[4]; G[6]=Rb[5];  G[7]=Jl[1];
    G[8]=Rb[6]; G[9]=Rb[7]; G[10]=Rb[8]; G[11]=Jl[2];
    #pragma unroll
    for (int i = 1; i < NJ; ++i) {
        const int p = PAR[i];
        const float* Ri = Rb + i*9;
        float r00=Ri[0],r01=Ri[1],r02=Ri[2];
        float r10=Ri[3],r11=Ri[4],r12=Ri[5];
        float r20=Ri[6],r21=Ri[7],r22=Ri[8];
        float px=Jl[p*3+0], py=Jl[p*3+1], pz=Jl[p*3+2];
        float tx = Jl[i*3+0] - (r00*px + r01*py + r02*pz);
        float ty = Jl[i*3+1] - (r10*px + r11*py + r12*pz);
        float tz = Jl[i*3+2] - (r20*px + r21*py + r22*pz);
        const float* gp = &G[p*12];
        float* gi = &G[i*12];
        #pragma unroll
        for (int rr = 0; rr < 3; ++rr) {
            float a0=gp[rr*4+0], a1=gp[rr*4+1], a2=gp[rr*4+2], a3=gp[rr*4+3];
            gi[rr*4+0] = a0*r00 + a1*r10 + a2*r20;
            gi[rr*4+1] = a0*r01 + a1*r11 + a2*r21;
            gi[rr*4+2] = a0*r02 + a1*r12 + a2*r22;
            gi[rr*4+3] = a0*tx + a1*ty + a2*tz + a3;
        }
    }
    #pragma unroll
    for (int i = 0; i < NJ; ++i) {
        float* gi = &G[i*12];
        float jx=Jl[i*3+0], jy=Jl[i*3+1], jz=Jl[i*3+2];
        #pragma unroll
        for (int rr = 0; rr < 3; ++rr)
            gi[rr*4+3] = gi[rr*4+3] - (gi[rr*4+0]*jx + gi[rr*4+1]*jy + gi[rr*4+2]*jz);
    }
    float* out = Gc + (size_t)b * 288;
    #pragma unroll
    for (int i = 0; i < 288; ++i) out[i] = G[i];
    if (doGmf) {
        short* gm = Gmf + (size_t)b * 512;
        #pragma unroll
        for (int q = 0; q < 3; ++q)
            for (int c = 0; c < 12; ++c) {
                #pragma unroll
                for (int e = 0; e < 8; ++e)
                    gm[(q*16 + c)*8 + e] = f2bf(G[(q*8 + e)*12 + c]);
            }
        #pragma unroll
        for (int q = 0; q < 3; ++q)
            for (int c = 12; c < 16; ++c)
                #pragma unroll
                for (int e = 0; e < 8; ++e) gm[(q*16 + c)*8 + e] = 0;
        #pragma unroll
        for (int c = 0; c < 16; ++c)
            #pragma unroll
            for (int e = 0; e < 8; ++e) gm[(48 + c)*8 + e] = 0;
    }
}

// ============ K7: 128-col streaming GEMM, f32 out (fallback) ============
__global__ __launch_bounds__(256, 2) void k_gemm(const short* __restrict__ Af,
        const short* __restrict__ Bf, const float* __restrict__ vt,
        float* __restrict__ vout, int B) {
    __shared__ float eld[64 * 128];
    const int t = threadIdx.x;
    const int wgid = blockIdx.x;
    const int bt = wgid & 7, nt = wgid >> 3;
    const int wave = t >> 6, lane = t & 63;
    const int wn = (wave & 1) * 64;
    const int q = lane >> 4, r16 = lane & 15;
    const int mfb = (wave >> 1) * 4, nfb = (wave & 1) * 4;

    const s16x8* Ab = (const s16x8*)(Af + (size_t)bt * FTILE);
    const s16x8* Bb = (const s16x8*)(Bf + (size_t)nt * FTILE);

    f32x4 acc[4][4];
    #pragma unroll
    for (int m = 0; m < 4; ++m)
        #pragma unroll
        for (int n = 0; n < 4; ++n)
            #pragma unroll
            for (int i = 0; i < 4; ++i) acc[m][n][i] = 0.0f;

    #pragma unroll
    for (int ks = 0; ks < 8; ++ks) {
        s16x8 a[4], b[4];
        #pragma unroll
        for (int m = 0; m < 4; ++m) a[m] = Ab[(ks*8 + mfb + m)*64 + lane];
        #pragma unroll
        for (int n = 0; n < 4; ++n) b[n] = Bb[(ks*8 + nfb + n)*64 + lane];
        #pragma unroll
        for (int m = 0; m < 4; ++m)
            #pragma unroll
            for (int n = 0; n < 4; ++n)
                acc[m][n] = __builtin_amdgcn_mfma_f32_16x16x32_bf16(a[m], b[n], acc[m][n], 0, 0, 0);
    }

    #pragma unroll
    for (int half = 0; half < 2; ++half) {
        if ((wave >> 1) == half) {
            #pragma unroll
            for (int m = 0; m < 4; ++m)
                #pragma unroll
                for (int n = 0; n < 4; ++n)
                    #pragma unroll
                    for (int i = 0; i < 4; ++i) {
                        int row_l = m*16 + q*4 + i;
                        int col = wn + n*16 + r16;
                        eld[row_l * 128 + (col ^ ((row_l & 7) << 2))] = acc[m][n][i];
                    }
        }
        __syncthreads();
        {
            const int c32 = t & 31;
            const int col = c32 * 4;
            const int rsub = (t >> 5) & 1;
            #pragma unroll
            for (int it = 0; it < 8; ++it) {
                int row_l = it * 8 + wave * 2 + rsub;
                int bg = bt * 128 + half * 64 + row_l;
                int rg = nt * 128 + col;
                f32x4 v = *(const f32x4*)&eld[row_l * 128 + (col ^ ((row_l & 7) << 2))];
                if (bg < B) {
                    float* dst = vout + (size_t)bg * NR + rg;
                    if (rg + 3 < NR) {
                        float4 tv = *(const float4*)(vt + rg);
                        v[0] += tv.x; v[1] += tv.y; v[2] += tv.z; v[3] += tv.w;
                        *(f4u*)dst = v;
                    } else {
                        #pragma unroll
                        for (int e = 0; e < 4; ++e)
                            if (rg + e < NR) dst[e] = v[e] + vt[rg + e];
                    }
                }
            }
        }
        __syncthreads();
    }
}

// ============ K7b: FUSED 64-batch x 192-col GEMM + MFMA skinning (R22-proven) ============
__global__ __launch_bounds__(256, 4) void k_gemm_skin(const short* __restrict__ Af,
        const short* __restrict__ Bf, const float* __restrict__ vt,
        const short* __restrict__ Gmf, const float* __restrict__ W,
        float* __restrict__ vout, int B) {
    __shared__ short elds[64 * ELDW];              // 33.8 KB bf16 v_posed (64 batches)
    const int t = threadIdx.x;
    const int wgid = blockIdx.x;
    const int nbt = B >> 6;                        // batch tiles of 64
    const int bt64 = wgid % nbt, nt = wgid / nbt;  // nt 0..107
    const int wave = t >> 6, lane = t & 63;
    const int q = lane >> 4, r16 = lane & 15;
    const int mfbase = (bt64 & 1) * 4;             // half of the 128-row A-frag tile
    const int nfb = wave * 3;                      // 3 n-frags per wave
    const int wn = wave * 48;

    const s16x8* Ab = (const s16x8*)(Af + (size_t)(bt64 >> 1) * FTILE);
    const s16x8* Bb = (const s16x8*)(Bf + (size_t)nt * FT2);

    f32x4 acc[4][3];
    #pragma unroll
    for (int m = 0; m < 4; ++m)
        #pragma unroll
        for (int n = 0; n < 3; ++n)
            #pragma unroll
            for (int i = 0; i < 4; ++i) acc[m][n][i] = 0.0f;

    #pragma unroll
    for (int ks = 0; ks < 8; ++ks) {
        s16x8 a[4], b[3];
        #pragma unroll
        for (int m = 0; m < 4; ++m) a[m] = Ab[(ks*8 + mfbase + m)*64 + lane];
        #pragma unroll
        for (int n = 0; n < 3; ++n) b[n] = Bb[(ks*12 + nfb + n)*64 + lane];
        #pragma unroll
        for (int m = 0; m < 4; ++m)
            #pragma unroll
            for (int n = 0; n < 3; ++n)
                acc[m][n] = __builtin_amdgcn_mfma_f32_16x16x32_bf16(a[m], b[n], acc[m][n], 0, 0, 0);
    }

    // per-n vt value + LDS short-offset (vert*4 + comp)
    float vtv[3];
    int sofs[3];
    #pragma unroll
    for (int n = 0; n < 3; ++n) {
        int col = wn + n*16 + r16;
        int rg = nt*192 + col;
        vtv[n] = (rg < NR) ? vt[rg] : 0.0f;
        int vert_ = col / 3;
        sofs[n] = vert_*4 + (col - vert_*3);
    }

    // W fragments for this tile's 64 verts
    s16x8 wf[4];
    int vert[4];
    bool vok[4];
    const int c16 = lane & 15;
    #pragma unroll
    for (int m = 0; m < 4; ++m) {
        vert[m] = nt*64 + m*16 + c16;
        vok[m] = (q < 3) && (vert[m] < NV);
        if (vok[m]) {
            const float* wp = W + (size_t)vert[m] * NJ + q*8;
            float4 f0 = *(const float4*)(wp);
            float4 f1 = *(const float4*)(wp + 4);
            wf[m][0]=f2bf(f0.x); wf[m][1]=f2bf(f0.y); wf[m][2]=f2bf(f0.z); wf[m][3]=f2bf(f0.w);
            wf[m][4]=f2bf(f1.x); wf[m][5]=f2bf(f1.y); wf[m][6]=f2bf(f1.z); wf[m][7]=f2bf(f1.w);
        } else {
            #pragma unroll
            for (int e = 0; e < 8; ++e) wf[m][e] = 0;
        }
    }

    // (a) all 4 waves write their acc into elds (disjoint column ranges)
    #pragma unroll
    for (int m = 0; m < 4; ++m)
        #pragma unroll
        for (int i = 0; i < 4; ++i) {
            int row_l = m*16 + q*4 + i;                // 0..63
            #pragma unroll
            for (int n = 0; n < 3; ++n)
                elds[row_l * ELDW + sofs[n]] = f2bf(acc[m][n][i] + vtv[n]);
        }
    __syncthreads();

    // (c) skin: each wave owns 16 batch rows; Gmf ping-pong prefetched
    {
        s16x8 afA, afB;
        int bl0 = wave * 16;
        int bgbase = bt64 * 64;
        afA = *(const s16x8*)&Gmf[((size_t)(bgbase + bl0) * 64 + lane) * 8];
        #pragma unroll 8
        for (int bb = 0; bb < 16; ++bb) {
            if (bb + 1 < 16) {
                const s16x8* nx = (const s16x8*)&Gmf[((size_t)(bgbase + bl0 + bb + 1) * 64 + lane) * 8];
                if (bb & 1) afA = *nx; else afB = *nx;
            }
            s16x8 af = (bb & 1) ? afB : afA;
            int bl = bl0 + bb;
            int bg = bgbase + bl;
            #pragma unroll
            for (int m = 0; m < 4; ++m) {
                s16x4 vd = *(const s16x4*)&elds[bl * ELDW + (m*16 + c16) * 4];
                f32x4 zz = {0.0f, 0.0f, 0.0f, 0.0f};
                f32x4 Tq = __builtin_amdgcn_mfma_f32_16x16x32_bf16(af, wf[m], zz, 0, 0, 0);
                if (vok[m]) {
                    float x = bf2fs((unsigned short)vd[0]);
                    float y = bf2fs((unsigned short)vd[1]);
                    float z = bf2fs((unsigned short)vd[2]);
                    float o = Tq[0]*x + Tq[1]*y + Tq[2]*z + Tq[3];
                    vout[(size_t)bg * NR + (size_t)vert[m] * 3 + q] = o;
                }
            }
        }
    }
}

// ============ K8: MFMA skinning, f32 in-place (fallback) ============
__global__ __launch_bounds__(256) void k_skin(float* __restrict__ vio,
        const float* __restrict__ W, const float* __restrict__ Gc, int B) {
    __shared__ short Gm[16 * 40];
    const int t = threadIdx.x;
    const int wave = t >> 6, lane = t & 63;
    const int q = lane >> 4, c = lane & 15;
    const int vb = blockIdx.x * 256 + wave * 64;
    const int b0 = blockIdx.y * 16;

    if (t < 320) ((int*)Gm)[t] = 0;

    s16x8 wf[4];
    #pragma unroll
    for (int m = 0; m < 4; ++m) {
        int vert = vb + m*16 + c;
        if (q < 3 && vert < NV) {
            const float* wp = W + (size_t)vert * NJ + q*8;
            float4 f0 = *(const float4*)(wp);
            float4 f1 = *(const float4*)(wp + 4);
            wf[m][0]=f2bf(f0.x); wf[m][1]=f2bf(f0.y); wf[m][2]=f2bf(f0.z); wf[m][3]=f2bf(f0.w);
            wf[m][4]=f2bf(f1.x); wf[m][5]=f2bf(f1.y); wf[m][6]=f2bf(f1.z); wf[m][7]=f2bf(f1.w);
        } else {
            #pragma unroll
            for (int e = 0; e < 8; ++e) wf[m][e] = 0;
        }
    }
    __syncthreads();

    for (int bb = 0; bb < 16; ++bb) {
        int b = b0 + bb;
        if (b >= B) break;
        {
            int i0 = t;
            int j0 = i0 / 12, c0 = i0 - j0*12;
            if (i0 < 288) Gm[c0*40 + j0] = f2bf(Gc[(size_t)b*288 + i0]);
            int i1 = t + 256;
            if (i1 < 288) {
                int j1 = i1 / 12, c1 = i1 - j1*12;
                Gm[c1*40 + j1] = f2bf(Gc[(size_t)b*288 + i1]);
            }
        }
        __syncthreads();

        s16x8 af = *(const s16x8*)&Gm[c*40 + q*8];
        #pragma unroll
        for (int m = 0; m < 4; ++m) {
            f32x4 zz = {0.0f, 0.0f, 0.0f, 0.0f};
            f32x4 acc = __builtin_amdgcn_mfma_f32_16x16x32_bf16(af, wf[m], zz, 0, 0, 0);
            int vert = vb + m*16 + c;
            bool ok = (q < 3) && (vert < NV);
            if (ok) {
                float* vp = vio + (size_t)b * NR + (size_t)vert * 3;
                float x = vp[0], y = vp[1], z = vp[2];
                float o = acc[0]*x + acc[1]*y + acc[2]*z + acc[3];
                vp[q] = o;
            }
        }
        __syncthreads();
    }
}

extern "C" void kernel_launch(void* const* d_in, const int* in_sizes, int n_in,
                              void* d_out, int out_size, void* d_ws, size_t ws_size,
                              hipStream_t stream) {
    const float* theta = (const float*)d_in[0];
    const float* beta  = (const float*)d_in[1];
    const float* sd    = (const float*)d_in[2];
    const float* pd    = (const float*)d_in[3];
    const float* Jreg  = (const float*)d_in[4];
    const float* vt    = (const float*)d_in[5];
    const float* W     = (const float*)d_in[6];
    float* out = (float*)d_out;

    const int B = in_sizes[0] / 72;

    float* vregion = out;
    float* Jout    = out + (size_t)B * NR;

    float* Rws   = (float*)d_ws;                          // B*216 f32
    float* Gcws  = Rws + (size_t)B * 216;                 // B*288 f32
    float* pfA   = Gcws + (size_t)B * 288;                // B*224 f32
    short* Afrag = (short*)(pfA + (size_t)B * 224);       // (B/128)*FTILE bf16
    short* Bfrag = Afrag + (size_t)(B/128) * FTILE;       // NT2*FT2 shorts (10.6 MB)
    short* Gmf   = Bfrag + (size_t)NT2 * FT2;             // B*512 bf16 (1 MB)

    size_t need_fuse = (size_t)B * 2912 + (size_t)(B/128) * FTILE * 2
                     + (size_t)NT2 * FT2 * 2 + (size_t)B * 512 * 2;
    const bool use_fuse = (ws_size >= need_fuse) && ((B & 127) == 0);

    float* part  = vregion;                               // d_out scratch pre-GEMM
    float* part2 = vregion + (size_t)NSPLIT * 72 * 224;
    float* JDt   = part2 + (size_t)8 * 72 * 224;

    const int rodblocks = (B*NJ + 255)/256;

    if (use_fuse) {
        k_prep<<<NSPLIT + 24*NT2 + rodblocks, 256, 0, stream>>>(
            theta, beta, pd, sd, vt, Jreg, Rws, pfA, Afrag, Bfrag, part, B);
    } else {
        k_rodrigues<<<rodblocks, 256, 0, stream>>>(theta, beta, Rws, pfA, Afrag, B);
        k_convB128<<<(NT*8*8*64)/256, 256, 0, stream>>>(pd, sd, Bfrag);
        k_jdirs<<<NSPLIT, 256, 0, stream>>>(pd, sd, vt, Jreg, part);
    }
    {
        dim3 grid(72, 8);
        k_jreduce1<<<grid, 256, 0, stream>>>(part, part2);
    }
    k_jreduce2<<<(72*224 + 255)/256, 256, 0, stream>>>(part2, JDt);
    k_J<<<B, 128, 0, stream>>>(pfA, JDt, Jout, B);
    k_chain<<<(B + 31)/32, 32, 0, stream>>>(Rws, Jout, Gcws, Gmf, use_fuse ? 1 : 0, B);

    if (use_fuse) {
        k_gemm_skin<<<NT2 * (B/64), 256, 0, stream>>>(Afrag, Bfrag, vt, Gmf, W, vregion, B);
    } else {
        k_gemm<<<NT * (B/128), 256, 0, stream>>>(Afrag, Bfrag, vt, vregion, B);
        dim3 grid((NV + 255)/256, (B + 15)/16);
        k_skin<<<grid, 256, 0, stream>>>(vregion, W, Gcws, B);
    }
}

// Round 25
// 103.599 us; speedup vs baseline: 1.0866x; 1.0866x over previous
//
#include <hip/hip_runtime.h>
#include <hip/hip_bf16.h>

#define NJ 24
#define NV 6890
#define NVP 6912
#define NR (NV*3)        // 20670 output rows per batch
#define NPF 207
#define KB 217           // 207 pf + 10 beta
#define KP 256           // padded K (8 x 32)
#define NT 162           // 128-col tiles (fallback path)
#define NT2 108          // 192-col tiles (64 whole verts each)
#define NSPLIT 512       // jdirs v-splits
#define VPB 14           // ceil(6890/512)
#define FTILE 32768      // A-tile shorts: 8 ks * 8 frag * 64 lane * 8
#define FT2   49152      // B-tile shorts (192-col)
#define ELDW 264         // elds row stride in shorts (64 verts*4 + 8 pad)

typedef short s16x8 __attribute__((ext_vector_type(8)));
typedef short s16x4 __attribute__((ext_vector_type(4)));
typedef float f32x4 __attribute__((ext_vector_type(4)));
typedef float f4u   __attribute__((ext_vector_type(4), aligned(4)));

__device__ constexpr int PAR[24] = {-1,0,0,0,1,2,3,4,5,6,7,8,9,9,9,12,13,14,16,17,18,19,20,21};

__device__ __forceinline__ short f2bf(float f) {
    __hip_bfloat16 h = __float2bfloat16(f);
    return *reinterpret_cast<short*>(&h);
}
__device__ __forceinline__ float bf2fs(unsigned short u) {
    unsigned int x = ((unsigned int)u) << 16;
    return __uint_as_float(x);
}

// A-fragment address for (row_in_tile, k)
__device__ __forceinline__ size_t frag_addr(int row128, int k) {
    int ks = k >> 5, q = (k >> 3) & 3, e = k & 7;
    int mf = row128 >> 4, r16 = row128 & 15;
    return ((size_t)(ks*8 + mf) * 64 + q*16 + r16) * 8 + e;
}

// -------- device bodies shared by fat kernel and fallbacks --------
__device__ __forceinline__ void rodrigues_body(int idx, const float* __restrict__ theta,
        const float* __restrict__ beta, float* __restrict__ Rws,
        float* __restrict__ pfA, short* __restrict__ Afrag, int B) {
    if (idx >= B * NJ) return;
    int b = idx / NJ, j = idx % NJ;
    float x = theta[b*72 + j*3 + 0];
    float y = theta[b*72 + j*3 + 1];
    float z = theta[b*72 + j*3 + 2];
    float n = sqrtf(x*x + y*y + z*z);
    float a = fmaxf(n, 1e-8f);
    float inv = 1.0f / a;
    float ix = x*inv, iy = y*inv, iz = z*inv;
    float c = cosf(a), s = sinf(a), t = 1.0f - c;
    float r[9];
    r[0] = t*ix*ix + c;     r[1] = t*ix*iy - s*iz;  r[2] = t*ix*iz + s*iy;
    r[3] = t*ix*iy + s*iz;  r[4] = t*iy*iy + c;     r[5] = t*iy*iz - s*ix;
    r[6] = t*ix*iz - s*iy;  r[7] = t*iy*iz + s*ix;  r[8] = t*iz*iz + c;
    float* Rp = Rws + (size_t)idx * 9;
    #pragma unroll
    for (int k = 0; k < 9; ++k) Rp[k] = r[k];

    int rb = b & 127;
    short* At = Afrag + (size_t)(b >> 7) * FTILE;
    float* pa = pfA + (size_t)b * 224;
    if (j >= 1) {
        #pragma unroll
        for (int kk = 0; kk < 9; ++kk) {
            int k = (j-1)*9 + kk;
            float f = r[kk] - ((kk == 0 || kk == 4 || kk == 8) ? 1.0f : 0.0f);
            At[frag_addr(rb, k)] = f2bf(f);
            pa[k] = f;
        }
    } else {
        #pragma unroll
        for (int kk = 0; kk < 10; ++kk) {
            int k = NPF + kk;
            float f = beta[b*10 + kk];
            At[frag_addr(rb, k)] = f2bf(f);
            pa[k] = f;
        }
        for (int k = KB; k < KP; ++k)
            At[frag_addr(rb, k)] = 0;
    }
}

__device__ __forceinline__ void convB192_body(int nt, int id,
        const float* __restrict__ pd, const float* __restrict__ sd,
        short* __restrict__ Bf) {
    int lane_ = id & 63;
    int fi = id >> 6;
    int nf = fi % 12, ks = fi / 12;
    int q = lane_ >> 4, r16 = lane_ & 15;
    int rg = nt*192 + nf*16 + r16;
    int k0 = ks*32 + q*8;
    s16x8 v;
    if (rg < NR) {
        if (k0 + 7 < NPF) {
            const float* p = pd + (size_t)rg * NPF + k0;
            #pragma unroll
            for (int k = 0; k < 8; ++k) v[k] = f2bf(p[k]);
        } else {
            #pragma unroll
            for (int k = 0; k < 8; ++k) {
                int col = k0 + k;
                float f = 0.0f;
                if (col < NPF)     f = pd[(size_t)rg * NPF + col];
                else if (col < KB) f = sd[(size_t)rg * 10 + (col - NPF)];
                v[k] = f2bf(f);
            }
        }
    } else {
        #pragma unroll
        for (int k = 0; k < 8; ++k) v[k] = 0;
    }
    *(s16x8*)&Bf[((size_t)nt * FT2) + (size_t)id * 8] = v;
}

// ============ K0: fat prep kernel — jdirs | convB192 | rodrigues ============
__global__ __launch_bounds__(256) void k_prep(const float* __restrict__ theta,
        const float* __restrict__ beta, const float* __restrict__ pd,
        const float* __restrict__ sd, const float* __restrict__ vt,
        const float* __restrict__ Jreg,
        float* __restrict__ Rws, float* __restrict__ pfA, short* __restrict__ Afrag,
        short* __restrict__ Bf, float* __restrict__ part, int B) {
    __shared__ float wjs[24][VPB];
    const int bid = blockIdx.x;
    const int t = threadIdx.x;
    if (bid < NSPLIT) {
        // ---- jdirs ----
        int bi = bid;
        int v0 = bi * VPB;
        int nv = NV - v0; if (nv > VPB) nv = VPB; if (nv < 0) nv = 0;
        for (int i = t; i < 24*VPB; i += 256) {
            int j = i / VPB, vv = i - j*VPB;
            wjs[j][vv] = (vv < nv) ? Jreg[(size_t)j * NV + v0 + vv] : 0.0f;
        }
        __syncthreads();
        int k = t;
        float acc[72];
        #pragma unroll
        for (int i = 0; i < 72; ++i) acc[i] = 0.0f;
        for (int vv = 0; vv < VPB; ++vv) {
            int v = v0 + vv;
            if (v >= NV) break;
            #pragma unroll
            for (int c = 0; c < 3; ++c) {
                int row = v*3 + c;
                float val = 0.0f;
                if (k < NPF)      val = pd[(size_t)row * NPF + k];
                else if (k < KB)  val = sd[(size_t)row * 10 + (k - NPF)];
                else if (k == KB) val = vt[row];
                #pragma unroll
                for (int j = 0; j < 24; ++j) acc[j*3 + c] += wjs[j][vv] * val;
            }
        }
        if (k < 224) {
            float* p = part + (size_t)bi * (72*224);
            #pragma unroll
            for (int i = 0; i < 72; ++i) p[i*224 + k] = acc[i];
        }
    } else if (bid < NSPLIT + 24*NT2) {
        // ---- convB192 ----
        int cb = bid - NSPLIT;
        int nt = cb / 24;
        int id = (cb % 24) * 256 + t;
        convB192_body(nt, id, pd, sd, Bf);
    } else {
        // ---- rodrigues ----
        int idx = (bid - NSPLIT - 24*NT2) * 256 + t;
        rodrigues_body(idx, theta, beta, Rws, pfA, Afrag, B);
    }
}

// ============ standalone kernels for fallback path ============
__global__ __launch_bounds__(256) void k_rodrigues(const float* __restrict__ theta,
        const float* __restrict__ beta, float* __restrict__ Rws,
        float* __restrict__ pfA, short* __restrict__ Afrag, int B) {
    rodrigues_body(blockIdx.x * blockDim.x + threadIdx.x, theta, beta, Rws, pfA, Afrag, B);
}

__global__ __launch_bounds__(256) void k_convB128(const float* __restrict__ pd,
        const float* __restrict__ sd, short* __restrict__ Bf) {
    int cid = blockIdx.x * 256 + threadIdx.x;
    int lane_ = cid & 63;
    int nf = (cid >> 6) & 7;
    int ks = (cid >> 9) & 7;
    int nt = cid >> 12;
    int q = lane_ >> 4, r16 = lane_ & 15;
    int rg = nt*128 + nf*16 + r16;
    int k0 = ks*32 + q*8;
    s16x8 v;
    if (rg < NR) {
        if (k0 + 7 < NPF) {
            const float* p = pd + (size_t)rg * NPF + k0;
            #pragma unroll
            for (int k = 0; k < 8; ++k) v[k] = f2bf(p[k]);
        } else {
            #pragma unroll
            for (int k = 0; k < 8; ++k) {
                int col = k0 + k;
                float f = 0.0f;
                if (col < NPF)     f = pd[(size_t)rg * NPF + col];
                else if (col < KB) f = sd[(size_t)rg * 10 + (col - NPF)];
                v[k] = f2bf(f);
            }
        }
    } else {
        #pragma unroll
        for (int k = 0; k < 8; ++k) v[k] = 0;
    }
    *(s16x8*)&Bf[(size_t)cid * 8] = v;
}

__global__ __launch_bounds__(256) void k_jdirs(const float* __restrict__ pd,
        const float* __restrict__ sd, const float* __restrict__ vt,
        const float* __restrict__ Jreg, float* __restrict__ part) {
    __shared__ float wjs[24][VPB];
    int bi = blockIdx.x;
    int v0 = bi * VPB;
    int nv = NV - v0; if (nv > VPB) nv = VPB; if (nv < 0) nv = 0;
    for (int i = threadIdx.x; i < 24*VPB; i += 256) {
        int j = i / VPB, vv = i - j*VPB;
        wjs[j][vv] = (vv < nv) ? Jreg[(size_t)j * NV + v0 + vv] : 0.0f;
    }
    __syncthreads();
    int k = threadIdx.x;
    float acc[72];
    #pragma unroll
    for (int i = 0; i < 72; ++i) acc[i] = 0.0f;
    for (int vv = 0; vv < VPB; ++vv) {
        int v = v0 + vv;
        if (v >= NV) break;
        #pragma unroll
        for (int c = 0; c < 3; ++c) {
            int row = v*3 + c;
            float val = 0.0f;
            if (k < NPF)      val = pd[(size_t)row * NPF + k];
            else if (k < KB)  val = sd[(size_t)row * 10 + (k - NPF)];
            else if (k == KB) val = vt[row];
            #pragma unroll
            for (int j = 0; j < 24; ++j) acc[j*3 + c] += wjs[j][vv] * val;
        }
    }
    if (k < 224) {
        float* p = part + (size_t)bi * (72*224);
        #pragma unroll
        for (int i = 0; i < 72; ++i) p[i*224 + k] = acc[i];
    }
}

// ============ K4a: reduce 512 -> 8 partials ============
__global__ __launch_bounds__(256) void k_jreduce1(const float* __restrict__ part,
        float* __restrict__ part2) {
    int i = blockIdx.x;            // 0..71
    int s = blockIdx.y;            // 0..7
    int k = threadIdx.x;
    if (k >= 224) return;
    float acc = 0.0f;
    #pragma unroll 4
    for (int bi = s*64; bi < s*64 + 64; ++bi)
        acc += part[(size_t)bi * (72*224) + i*224 + k];
    part2[((size_t)s * 72 + i) * 224 + k] = acc;
}

// ============ K4b: reduce 8 -> JDt[k][72] ============
__global__ __launch_bounds__(256) void k_jreduce2(const float* __restrict__ part2,
        float* __restrict__ JDt) {
    int e = blockIdx.x * 256 + threadIdx.x;
    if (e >= 72*224) return;
    int i = e / 224, k = e - i*224;
    float s = 0.0f;
    #pragma unroll
    for (int ss = 0; ss < 8; ++ss)
        s += part2[((size_t)ss * 72 + i) * 224 + k];
    if (k < 218) JDt[k*72 + i] = s;
}

// ============ K5: J ============
__global__ __launch_bounds__(128) void k_J(const float* __restrict__ pfA,
        const float* __restrict__ JDt, float* __restrict__ Jout, int B) {
    int b = blockIdx.x, t = threadIdx.x;
    if (t >= 72) return;
    const float* pa = pfA + (size_t)b * 224;
    float acc = JDt[217*72 + t];
    #pragma unroll 7
    for (int k = 0; k < KB; ++k) acc += pa[k] * JDt[k*72 + t];
    Jout[(size_t)b * 72 + t] = acc;
}

// ============ K6: kinematic chain -> G_corr (+ optional Gmf fragments) ============
__global__ __launch_bounds__(32) void k_chain(const float* __restrict__ Rg,
        const float* __restrict__ Jg, float* __restrict__ Gc,
        short* __restrict__ Gmf, int doGmf, int B) {
    __shared__ float Gs[32 * 289];
    int b = blockIdx.x * 32 + threadIdx.x;
    if (b >= B) return;
    float* G = &Gs[threadIdx.x * 289];
    float Jl[72];
    const float* Jb = Jg + (size_t)b * 72;
    #pragma unroll
    for (int i = 0; i < 72; ++i) Jl[i] = Jb[i];
    const float* Rb = Rg + (size_t)b * 216;
    G[0]=Rb[0]; G[1]=Rb[1]; G[2]=Rb[2];  G[3]=Jl[0];
    G[4]=Rb[3]; G[5]=Rb[4]; G[6]=Rb[5];  G[7]=Jl[1];
    G[8]=Rb[6]; G[9]=Rb[7]; G[10]=Rb[8]; G[11]=Jl[2];
    #pragma unroll
    for (int i = 1; i < NJ; ++i) {
        const int p = PAR[i];
        const float* Ri = Rb + i*9;
        float r00=Ri[0],r01=Ri[1],r02=Ri[2];
        float r10=Ri[3],r11=Ri[4],r12=Ri[5];
        float r20=Ri[6],r21=Ri[7],r22=Ri[8];
        float px=Jl[p*3+0], py=Jl[p*3+1], pz=Jl[p*3+2];
        float tx = Jl[i*3+0] - (r00*px + r01*py + r02*pz);
        float ty = Jl[i*3+1] - (r10*px + r11*py + r12*pz);
        float tz = Jl[i*3+2] - (r20*px + r21*py + r22*pz);
        const float* gp = &G[p*12];
        float* gi = &G[i*12];
        #pragma unroll
        for (int rr = 0; rr < 3; ++rr) {
            float a0=gp[rr*4+0], a1=gp[rr*4+1], a2=gp[rr*4+2], a3=gp[rr*4+3];
            gi[rr*4+0] = a0*r00 + a1*r10 + a2*r20;
            gi[rr*4+1] = a0*r01 + a1*r11 + a2*r21;
            gi[rr*4+2] = a0*r02 + a1*r12 + a2*r22;
            gi[rr*4+3] = a0*tx + a1*ty + a2*tz + a3;
        }
    }
    #pragma unroll
    for (int i = 0; i < NJ; ++i) {
        float* gi = &G[i*12];
        float jx=Jl[i*3+0], jy=Jl[i*3+1], jz=Jl[i*3+2];
        #pragma unroll
        for (int rr = 0; rr < 3; ++rr)
            gi[rr*4+3] = gi[rr*4+3] - (gi[rr*4+0]*jx + gi[rr*4+1]*jy + gi[rr*4+2]*jz);
    }
    float* out = Gc + (size_t)b * 288;
    #pragma unroll
    for (int i = 0; i < 288; ++i) out[i] = G[i];
    if (doGmf) {
        short* gm = Gmf + (size_t)b * 512;
        #pragma unroll
        for (int q = 0; q < 3; ++q)
            for (int c = 0; c < 12; ++c) {
                #pragma unroll
                for (int e = 0; e < 8; ++e)
                    gm[(q*16 + c)*8 + e] = f2bf(G[(q*8 + e)*12 + c]);
            }
        #pragma unroll
        for (int q = 0; q < 3; ++q)
            for (int c = 12; c < 16; ++c)
                #pragma unroll
                for (int e = 0; e < 8; ++e) gm[(q*16 + c)*8 + e] = 0;
        #pragma unroll
        for (int c = 0; c < 16; ++c)
            #pragma unroll
            for (int e = 0; e < 8; ++e) gm[(48 + c)*8 + e] = 0;
    }
}

// ============ K7: 128-col streaming GEMM, f32 out (fallback) ============
__global__ __launch_bounds__(256, 2) void k_gemm(const short* __restrict__ Af,
        const short* __restrict__ Bf, const float* __restrict__ vt,
        float* __restrict__ vout, int B) {
    __shared__ float eld[64 * 128];
    const int t = threadIdx.x;
    const int wgid = blockIdx.x;
    const int bt = wgid & 7, nt = wgid >> 3;
    const int wave = t >> 6, lane = t & 63;
    const int wn = (wave & 1) * 64;
    const int q = lane >> 4, r16 = lane & 15;
    const int mfb = (wave >> 1) * 4, nfb = (wave & 1) * 4;

    const s16x8* Ab = (const s16x8*)(Af + (size_t)bt * FTILE);
    const s16x8* Bb = (const s16x8*)(Bf + (size_t)nt * FTILE);

    f32x4 acc[4][4];
    #pragma unroll
    for (int m = 0; m < 4; ++m)
        #pragma unroll
        for (int n = 0; n < 4; ++n)
            #pragma unroll
            for (int i = 0; i < 4; ++i) acc[m][n][i] = 0.0f;

    #pragma unroll
    for (int ks = 0; ks < 8; ++ks) {
        s16x8 a[4], b[4];
        #pragma unroll
        for (int m = 0; m < 4; ++m) a[m] = Ab[(ks*8 + mfb + m)*64 + lane];
        #pragma unroll
        for (int n = 0; n < 4; ++n) b[n] = Bb[(ks*8 + nfb + n)*64 + lane];
        #pragma unroll
        for (int m = 0; m < 4; ++m)
            #pragma unroll
            for (int n = 0; n < 4; ++n)
                acc[m][n] = __builtin_amdgcn_mfma_f32_16x16x32_bf16(a[m], b[n], acc[m][n], 0, 0, 0);
    }

    #pragma unroll
    for (int half = 0; half < 2; ++half) {
        if ((wave >> 1) == half) {
            #pragma unroll
            for (int m = 0; m < 4; ++m)
                #pragma unroll
                for (int n = 0; n < 4; ++n)
                    #pragma unroll
                    for (int i = 0; i < 4; ++i) {
                        int row_l = m*16 + q*4 + i;
                        int col = wn + n*16 + r16;
                        eld[row_l * 128 + (col ^ ((row_l & 7) << 2))] = acc[m][n][i];
                    }
        }
        __syncthreads();
        {
            const int c32 = t & 31;
            const int col = c32 * 4;
            const int rsub = (t >> 5) & 1;
            #pragma unroll
            for (int it = 0; it < 8; ++it) {
                int row_l = it * 8 + wave * 2 + rsub;
                int bg = bt * 128 + half * 64 + row_l;
                int rg = nt * 128 + col;
                f32x4 v = *(const f32x4*)&eld[row_l * 128 + (col ^ ((row_l & 7) << 2))];
                if (bg < B) {
                    float* dst = vout + (size_t)bg * NR + rg;
                    if (rg + 3 < NR) {
                        float4 tv = *(const float4*)(vt + rg);
                        v[0] += tv.x; v[1] += tv.y; v[2] += tv.z; v[3] += tv.w;
                        *(f4u*)dst = v;
                    } else {
                        #pragma unroll
                        for (int e = 0; e < 4; ++e)
                            if (rg + e < NR) dst[e] = v[e] + vt[rg + e];
                    }
                }
            }
        }
        __syncthreads();
    }
}

// ============ K7b: FUSED 64-batch x 192-col GEMM + MFMA skinning (R22-proven) ============
__global__ __launch_bounds__(256, 4) void k_gemm_skin(const short* __restrict__ Af,
        const short* __restrict__ Bf, const float* __restrict__ vt,
        const short* __restrict__ Gmf, const float* __restrict__ W,
        float* __restrict__ vout, int B) {
    __shared__ short elds[64 * ELDW];              // 33.8 KB bf16 v_posed (64 batches)
    const int t = threadIdx.x;
    const int wgid = blockIdx.x;
    const int nbt = B >> 6;                        // batch tiles of 64
    const int bt64 = wgid % nbt, nt = wgid / nbt;  // nt 0..107
    const int wave = t >> 6, lane = t & 63;
    const int q = lane >> 4, r16 = lane & 15;
    const int mfbase = (bt64 & 1) * 4;             // half of the 128-row A-frag tile
    const int nfb = wave * 3;                      // 3 n-frags per wave
    const int wn = wave * 48;

    const s16x8* Ab = (const s16x8*)(Af + (size_t)(bt64 >> 1) * FTILE);
    const s16x8* Bb = (const s16x8*)(Bf + (size_t)nt * FT2);

    f32x4 acc[4][3];
    #pragma unroll
    for (int m = 0; m < 4; ++m)
        #pragma unroll
        for (int n = 0; n < 3; ++n)
            #pragma unroll
            for (int i = 0; i < 4; ++i) acc[m][n][i] = 0.0f;

    #pragma unroll
    for (int ks = 0; ks < 8; ++ks) {
        s16x8 a[4], b[3];
        #pragma unroll
        for (int m = 0; m < 4; ++m) a[m] = Ab[(ks*8 + mfbase + m)*64 + lane];
        #pragma unroll
        for (int n = 0; n < 3; ++n) b[n] = Bb[(ks*12 + nfb + n)*64 + lane];
        #pragma unroll
        for (int m = 0; m < 4; ++m)
            #pragma unroll
            for (int n = 0; n < 3; ++n)
                acc[m][n] = __builtin_amdgcn_mfma_f32_16x16x32_bf16(a[m], b[n], acc[m][n], 0, 0, 0);
    }

    // per-n vt value + LDS short-offset (vert*4 + comp)
    float vtv[3];
    int sofs[3];
    #pragma unroll
    for (int n = 0; n < 3; ++n) {
        int col = wn + n*16 + r16;
        int rg = nt*192 + col;
        vtv[n] = (rg < NR) ? vt[rg] : 0.0f;
        int vert_ = col / 3;
        sofs[n] = vert_*4 + (col - vert_*3);
    }

    // W fragments for this tile's 64 verts
    s16x8 wf[4];
    int vert[4];
    bool vok[4];
    const int c16 = lane & 15;
    #pragma unroll
    for (int m = 0; m < 4; ++m) {
        vert[m] = nt*64 + m*16 + c16;
        vok[m] = (q < 3) && (vert[m] < NV);
        if (vok[m]) {
            const float* wp = W + (size_t)vert[m] * NJ + q*8;
            float4 f0 = *(const float4*)(wp);
            float4 f1 = *(const float4*)(wp + 4);
            wf[m][0]=f2bf(f0.x); wf[m][1]=f2bf(f0.y); wf[m][2]=f2bf(f0.z); wf[m][3]=f2bf(f0.w);
            wf[m][4]=f2bf(f1.x); wf[m][5]=f2bf(f1.y); wf[m][6]=f2bf(f1.z); wf[m][7]=f2bf(f1.w);
        } else {
            #pragma unroll
            for (int e = 0; e < 8; ++e) wf[m][e] = 0;
        }
    }

    // (a) all 4 waves write their acc into elds (disjoint column ranges)
    #pragma unroll
    for (int m = 0; m < 4; ++m)
        #pragma unroll
        for (int i = 0; i < 4; ++i) {
            int row_l = m*16 + q*4 + i;                // 0..63
            #pragma unroll
            for (int n = 0; n < 3; ++n)
                elds[row_l * ELDW + sofs[n]] = f2bf(acc[m][n][i] + vtv[n]);
        }
    __syncthreads();

    // (c) skin: each wave owns 16 batch rows; Gmf ping-pong prefetched
    {
        s16x8 afA, afB;
        int bl0 = wave * 16;
        int bgbase = bt64 * 64;
        afA = *(const s16x8*)&Gmf[((size_t)(bgbase + bl0) * 64 + lane) * 8];
        #pragma unroll 8
        for (int bb = 0; bb < 16; ++bb) {
            if (bb + 1 < 16) {
                const s16x8* nx = (const s16x8*)&Gmf[((size_t)(bgbase + bl0 + bb + 1) * 64 + lane) * 8];
                if (bb & 1) afA = *nx; else afB = *nx;
            }
            s16x8 af = (bb & 1) ? afB : afA;
            int bl = bl0 + bb;
            int bg = bgbase + bl;
            #pragma unroll
            for (int m = 0; m < 4; ++m) {
                s16x4 vd = *(const s16x4*)&elds[bl * ELDW + (m*16 + c16) * 4];
                f32x4 zz = {0.0f, 0.0f, 0.0f, 0.0f};
                f32x4 Tq = __builtin_amdgcn_mfma_f32_16x16x32_bf16(af, wf[m], zz, 0, 0, 0);
                if (vok[m]) {
                    float x = bf2fs((unsigned short)vd[0]);
                    float y = bf2fs((unsigned short)vd[1]);
                    float z = bf2fs((unsigned short)vd[2]);
                    float o = Tq[0]*x + Tq[1]*y + Tq[2]*z + Tq[3];
                    vout[(size_t)bg * NR + (size_t)vert[m] * 3 + q] = o;
                }
            }
        }
    }
}

// ============ K8: MFMA skinning, f32 in-place (fallback) ============
__global__ __launch_bounds__(256) void k_skin(float* __restrict__ vio,
        const float* __restrict__ W, const float* __restrict__ Gc, int B) {
    __shared__ short Gm[16 * 40];
    const int t = threadIdx.x;
    const int wave = t >> 6, lane = t & 63;
    const int q = lane >> 4, c = lane & 15;
    const int vb = blockIdx.x * 256 + wave * 64;
    const int b0 = blockIdx.y * 16;

    if (t < 320) ((int*)Gm)[t] = 0;

    s16x8 wf[4];
    #pragma unroll
    for (int m = 0; m < 4; ++m) {
        int vert = vb + m*16 + c;
        if (q < 3 && vert < NV) {
            const float* wp = W + (size_t)vert * NJ + q*8;
            float4 f0 = *(const float4*)(wp);
            float4 f1 = *(const float4*)(wp + 4);
            wf[m][0]=f2bf(f0.x); wf[m][1]=f2bf(f0.y); wf[m][2]=f2bf(f0.z); wf[m][3]=f2bf(f0.w);
            wf[m][4]=f2bf(f1.x); wf[m][5]=f2bf(f1.y); wf[m][6]=f2bf(f1.z); wf[m][7]=f2bf(f1.w);
        } else {
            #pragma unroll
            for (int e = 0; e < 8; ++e) wf[m][e] = 0;
        }
    }
    __syncthreads();

    for (int bb = 0; bb < 16; ++bb) {
        int b = b0 + bb;
        if (b >= B) break;
        {
            int i0 = t;
            int j0 = i0 / 12, c0 = i0 - j0*12;
            if (i0 < 288) Gm[c0*40 + j0] = f2bf(Gc[(size_t)b*288 + i0]);
            int i1 = t + 256;
            if (i1 < 288) {
                int j1 = i1 / 12, c1 = i1 - j1*12;
                Gm[c1*40 + j1] = f2bf(Gc[(size_t)b*288 + i1]);
            }
        }
        __syncthreads();

        s16x8 af = *(const s16x8*)&Gm[c*40 + q*8];
        #pragma unroll
        for (int m = 0; m < 4; ++m) {
            f32x4 zz = {0.0f, 0.0f, 0.0f, 0.0f};
            f32x4 acc = __builtin_amdgcn_mfma_f32_16x16x32_bf16(af, wf[m], zz, 0, 0, 0);
            int vert = vb + m*16 + c;
            bool ok = (q < 3) && (vert < NV);
            if (ok) {
                float* vp = vio + (size_t)b * NR + (size_t)vert * 3;
                float x = vp[0], y = vp[1], z = vp[2];
                float o = acc[0]*x + acc[1]*y + acc[2]*z + acc[3];
                vp[q] = o;
            }
        }
        __syncthreads();
    }
}

extern "C" void kernel_launch(void* const* d_in, const int* in_sizes, int n_in,
                              void* d_out, int out_size, void* d_ws, size_t ws_size,
                              hipStream_t stream) {
    const float* theta = (const float*)d_in[0];
    const float* beta  = (const float*)d_in[1];
    const float* sd    = (const float*)d_in[2];
    const float* pd    = (const float*)d_in[3];
    const float* Jreg  = (const float*)d_in[4];
    const float* vt    = (const float*)d_in[5];
    const float* W     = (const float*)d_in[6];
    float* out = (float*)d_out;

    const int B = in_sizes[0] / 72;

    float* vregion = out;
    float* Jout    = out + (size_t)B * NR;

    float* Rws   = (float*)d_ws;                          // B*216 f32
    float* Gcws  = Rws + (size_t)B * 216;                 // B*288 f32
    float* pfA   = Gcws + (size_t)B * 288;                // B*224 f32
    short* Afrag = (short*)(pfA + (size_t)B * 224);       // (B/128)*FTILE bf16
    short* Bfrag = Afrag + (size_t)(B/128) * FTILE;       // NT2*FT2 shorts (10.6 MB)
    short* Gmf   = Bfrag + (size_t)NT2 * FT2;             // B*512 bf16 (1 MB)

    size_t need_fuse = (size_t)B * 2912 + (size_t)(B/128) * FTILE * 2
                     + (size_t)NT2 * FT2 * 2 + (size_t)B * 512 * 2;
    const bool use_fuse = (ws_size >= need_fuse) && ((B & 127) == 0);

    float* part  = vregion;                               // d_out scratch pre-GEMM
    float* part2 = vregion + (size_t)NSPLIT * 72 * 224;
    float* JDt   = part2 + (size_t)8 * 72 * 224;

    const int rodblocks = (B*NJ + 255)/256;

    if (use_fuse) {
        k_prep<<<NSPLIT + 24*NT2 + rodblocks, 256, 0, stream>>>(
            theta, beta, pd, sd, vt, Jreg, Rws, pfA, Afrag, Bfrag, part, B);
    } else {
        k_rodrigues<<<rodblocks, 256, 0, stream>>>(theta, beta, Rws, pfA, Afrag, B);
        k_convB128<<<(NT*8*8*64)/256, 256, 0, stream>>>(pd, sd, Bfrag);
        k_jdirs<<<NSPLIT, 256, 0, stream>>>(pd, sd, vt, Jreg, part);
    }
    {
        dim3 grid(72, 8);
        k_jreduce1<<<grid, 256, 0, stream>>>(part, part2);
    }
    k_jreduce2<<<(72*224 + 255)/256, 256, 0, stream>>>(part2, JDt);
    k_J<<<B, 128, 0, stream>>>(pfA, JDt, Jout, B);
    k_chain<<<(B + 31)/32, 32, 0, stream>>>(Rws, Jout, Gcws, Gmf, use_fuse ? 1 : 0, B);

    if (use_fuse) {
        k_gemm_skin<<<NT2 * (B/64), 256, 0, stream>>>(Afrag, Bfrag, vt, Gmf, W, vregion, B);
    } else {
        k_gemm<<<NT * (B/128), 256, 0, stream>>>(Afrag, Bfrag, vt, vregion, B);
        dim3 grid((NV + 255)/256, (B + 15)/16);
        k_skin<<<grid, 256, 0, stream>>>(vregion, W, Gcws, B);
    }
}